// Round 4
// baseline (231.907 us; speedup 1.0000x reference)
//
#include <hip/hip_runtime.h>
#include <math.h>

#define BATCH 64
#define TT 24
#define HW 65536
#define PIX 50
#define NN 24
#define GAMMA_F 0.001f
#define INVG 1000.0f
#define BIGF 100000000.0f
#define CAP 2048
#define NBIN 32768   // bins over ordered-key bits [31:17]

struct BlockPart { double s; double t; };

__device__ __forceinline__ unsigned ordered_key(float f) {
    unsigned u = __float_as_uint(f);
    return (u & 0x80000000u) ? ~u : (u | 0x80000000u);
}

// One block per batch: top-50 radix select + 50 soft-DTW fwd/bwd + partial sums.
__global__ __launch_bounds__(1024) void mono_kernel(
        const float* __restrict__ pred, const float* __restrict__ truth,
        const float* __restrict__ mask, BlockPart* __restrict__ parts) {
    __shared__ union {
        unsigned hist[NBIN];                                   // 128 KB, phase 1a
        struct { unsigned ck[CAP]; unsigned ci[CAP]; } c;      // 16 KB, phase 1b
        struct { float R[16][64][25]; float P[16][64]; } d;    // 106.5 KB, phase 2
    } U;
    __shared__ unsigned wtot[16], wsuf[16];
    __shared__ unsigned s_bin, ncand;
    __shared__ int topIdx[PIX];
    __shared__ float waccS[16], waccT[16];

    const int tid  = threadIdx.x;
    const int w    = tid >> 6;
    const int lane = tid & 63;
    const int b    = blockIdx.x;

    // ======================= PHASE 1: top-50 (exact lax.top_k order) ====
    const float4* m4 = (const float4*)(mask + (size_t)b * HW);
    if (tid == 0) ncand = 0;
    #pragma unroll
    for (int k = 0; k < NBIN / 1024; ++k) U.hist[tid + 1024 * k] = 0;
    __syncthreads();

    for (int c = tid; c < HW / 4; c += 1024) {
        float4 v = m4[c];
        atomicAdd(&U.hist[ordered_key(v.x) >> 17], 1u);
        atomicAdd(&U.hist[ordered_key(v.y) >> 17], 1u);
        atomicAdd(&U.hist[ordered_key(v.z) >> 17], 1u);
        atomicAdd(&U.hist[ordered_key(v.w) >> 17], 1u);
    }
    __syncthreads();

    // per-thread partial over 32 bins (rotated reads -> 2-way conflict = free)
    int base = tid * 32;
    int rot  = tid & 31;
    unsigned p = 0;
    #pragma unroll
    for (int k = 0; k < 32; ++k) p += U.hist[base + ((k + rot) & 31)];

    // wave-level inclusive suffix scan (in-register, no barriers)
    unsigned v = p;
    #pragma unroll
    for (int off = 1; off < 64; off <<= 1) {
        unsigned t = __shfl_down(v, off);
        if (lane + off < 64) v += t;
    }
    if (lane == 0) wtot[w] = v;
    __syncthreads();
    if (w == 0 && lane < 16) {
        unsigned x = wtot[lane];
        unsigned y = x;
        #pragma unroll
        for (int off = 1; off < 16; off <<= 1) {
            unsigned t = __shfl_down(y, off);
            if (lane + off < 16) y += t;
        }
        wsuf[lane] = y - x;           // exclusive suffix over higher waves
    }
    __syncthreads();

    {   // find crossing bin: max bin with S(bin) >= PIX
        unsigned Sprev = (v - p) + wsuf[w];     // S(32t+32)
        for (int bsub = 31; bsub >= 0; --bsub) {
            unsigned S = Sprev + U.hist[base + bsub];
            if (S >= PIX && Sprev < PIX) s_bin = (unsigned)(base + bsub);
            Sprev = S;
        }
    }
    __syncthreads();                  // all hist reads done; cand may alias
    unsigned thresh = s_bin << 17;

    for (int c = tid; c < HW / 4; c += 1024) {
        float4 v4 = m4[c];
        float vv[4] = {v4.x, v4.y, v4.z, v4.w};
        #pragma unroll
        for (int e = 0; e < 4; ++e) {
            unsigned key = ordered_key(vv[e]);
            if (key >= thresh) {
                unsigned pos = atomicAdd(&ncand, 1u);
                if (pos < CAP) { U.c.ck[pos] = key; U.c.ci[pos] = (unsigned)(4 * c + e); }
            }
        }
    }
    __syncthreads();

    int nc = (int)min(ncand, (unsigned)CAP);
    for (int c = tid; c < nc; c += 1024) {
        unsigned long long me =
            ((unsigned long long)U.c.ck[c] << 32) | (unsigned long long)(~U.c.ci[c]);
        int rank = 0;
        for (int j = 0; j < nc; ++j) {
            unsigned long long o =
                ((unsigned long long)U.c.ck[j] << 32) | (unsigned long long)(~U.c.ci[j]);
            rank += (o > me);
        }
        if (rank < PIX) topIdx[rank] = (int)U.c.ci[c];
    }
    __syncthreads();                  // topIdx ready; U.d may alias cand

    // ======================= PHASE 2: 50 soft-DTW problems ==============
    // Wave-private: 2 problems per wave (rows in lanes 0-23 and 32-55),
    // register wavefront, R rows staged in wave-private LDS for backward.
    const int half = lane >> 5;
    const int r    = lane & 31;
    const bool rowAct = (r < NN);
    float accS = 0.0f, accT = 0.0f;

    for (int q = 0; q < 2; ++q) {
        if (q * 32 + w * 2 >= PIX) continue;      // wave-uniform skip
        int np = q * 32 + w * 2 + half;           // problem 0..49 in this batch

        float tv = 0.0f, pv = 0.0f;
        if (rowAct) {
            int f  = np * NN + r;                 // within-batch flat (t,p) index
            int t  = f / PIX;
            int pp = f - t * PIX;
            size_t a = (size_t)(b * TT + t) * HW + (size_t)topIdx[pp];
            tv = truth[a];
            pv = pred[a];
        }
        U.d.P[w][lane] = pv;                      // wave-private p table

        // ---- forward: lane r holds row i=r+1; step s computes R[i][s-i] ----
        float Rprev = BIGF, Rprev2 = BIGF;        // R[i][j-1], R[i][j-2]
        #pragma unroll
        for (int s = 2; s <= 2 * NN; ++s) {
            int j = s - 1 - r;
            bool act = rowAct && (j >= 1) && (j <= NN);
            float up   = __shfl_up(Rprev, 1);     // R[i-1][j]   (lane r-1, step s-1)
            float diag = __shfl_up(Rprev2, 1);    // R[i-1][j-1] (lane r-1, step s-2)
            int jc = j - 1; jc = jc < 0 ? 0 : (jc > NN - 1 ? NN - 1 : jc);
            float pj = U.d.P[w][(half << 5) + jc];
            if (r == 0) { up = BIGF; diag = (s == 2) ? 0.0f : BIGF; }
            float mn = fminf(diag, fminf(up, Rprev));
            float z = __expf((mn - diag) * INVG) + __expf((mn - up) * INVG)
                    + __expf((mn - Rprev) * INVG);
            float d = tv - pj;
            float Rnew = d * d + mn - GAMMA_F * __logf(z);
            if (act) {
                U.d.R[w][lane][j - 1] = Rnew;     // stage for backward
                Rprev2 = Rprev;
                Rprev  = Rnew;
            }
        }
        // lane r==23 now holds R[24][24] in Rprev.

        // ---- backward: E[i][j] = a*E[i+1][j] + b*E[i][j+1] + c*E[i+1][j+1] ----
        float Eprev = 0.0f, Eprev2 = 0.0f;        // own E[i][j+1], E[i][j+2]
        if (r == NN - 1) Eprev = 1.0f;            // s=48: E[24][24]=1 (Omega term = 0)
        float tnext = __shfl_down(tv, 1);         // t[i] (row i+1's value)
        #pragma unroll
        for (int s = 2 * NN - 1; s >= 2; --s) {
            int j = s - 1 - r;
            bool act = rowAct && (j >= 1) && (j <= NN);
            float eUp   = __shfl_down(Eprev, 1);  // E[i+1][j]   (lane 24 stays 0)
            float eDiag = __shfl_down(Eprev2, 1); // E[i+1][j+1]
            int jc  = j - 1; jc  = jc  < 0 ? 0 : (jc  > NN - 1 ? NN - 1 : jc);
            int jc2 = j;     jc2 = jc2 < 0 ? 0 : (jc2 > NN - 1 ? NN - 1 : jc2);
            int lup = (r < NN - 1) ? lane + 1 : lane;
            float rij    = U.d.R[w][lane][jc];
            float rRight = (j >= NN)               ? -INFINITY : U.d.R[w][lane][jc2];
            float rDown  = (r == NN - 1)           ? -INFINITY : U.d.R[w][lup][jc];
            float rDiag  = (r == NN - 1 || j >= NN)? -INFINITY : U.d.R[w][lup][jc2];
            float pjm1 = U.d.P[w][(half << 5) + jc];
            float pj   = U.d.P[w][(half << 5) + jc2];
            float da = tnext - pjm1; da *= da;    // D[i+1][j]
            float db = tv - pj;      db *= db;    // D[i][j+1]
            float dc = tnext - pj;   dc *= dc;    // D[i+1][j+1]
            float aw = __expf((rDown  - rij - da) * INVG);
            float bw = __expf((rRight - rij - db) * INVG);
            float cw = __expf((rDiag  - rij - dc) * INVG);
            float Enew = aw * eUp + bw * Eprev + cw * eDiag;
            if (act) {
                float dd = (float)(r + 1 - j);
                accT += Enew * dd * dd;           // E * Omega, own row slice
                Eprev2 = Eprev;
                Eprev  = Enew;
            }
        }
        if (r == NN - 1) accS += Rprev;           // loss_shape contribution
    }

    // ---- block reduction (deterministic: fixed butterfly + fixed order) ----
    #pragma unroll
    for (int off = 32; off > 0; off >>= 1) {
        accS += __shfl_xor(accS, off);
        accT += __shfl_xor(accT, off);
    }
    if (lane == 0) { waccS[w] = accS; waccT[w] = accT; }
    __syncthreads();
    if (tid == 0) {
        double S = 0.0, T = 0.0;
        for (int i = 0; i < 16; ++i) { S += (double)waccS[i]; T += (double)waccT[i]; }
        parts[b].s = S;
        parts[b].t = T;
    }
}

// ---------------- Kernel 2: deterministic final reduction (1 wave) -------
__global__ __launch_bounds__(64) void finalize_kernel(
        const BlockPart* __restrict__ parts, float* __restrict__ out) {
    int lane = threadIdx.x;
    double S = parts[lane].s;
    double T = parts[lane].t;
    #pragma unroll
    for (int off = 32; off > 0; off >>= 1) {
        S += __shfl_xor(S, off);
        T += __shfl_xor(T, off);
    }
    if (lane == 0) {
        double loss_shape    = S / (double)(BATCH * PIX);
        double loss_temporal = T / ((double)(BATCH * PIX) * (double)(NN * NN));
        out[0] = (float)(0.1 * loss_shape + 0.9 * loss_temporal);
    }
}

extern "C" void kernel_launch(void* const* d_in, const int* in_sizes, int n_in,
                              void* d_out, int out_size, void* d_ws, size_t ws_size,
                              hipStream_t stream) {
    const float* pred  = (const float*)d_in[0];
    const float* truth = (const float*)d_in[1];
    const float* mask  = (const float*)d_in[2];

    BlockPart* parts = (BlockPart*)d_ws;          // 64 * 16 B = 1 KB

    mono_kernel<<<BATCH, 1024, 0, stream>>>(pred, truth, mask, parts);
    finalize_kernel<<<1, 64, 0, stream>>>(parts, (float*)d_out);
}

// Round 5
// 125.567 us; speedup vs baseline: 1.8469x; 1.8469x over previous
//
#include <hip/hip_runtime.h>
#include <math.h>

#define BATCH 64
#define TT 24
#define HW 65536
#define PIX 50
#define NN 24
#define GAMMA_F 0.001f
#define INVG 1000.0f
#define BIGF 100000000.0f
#define CAP 2048
#define NBIN 32768   // bins over ordered-key bits [31:17]
#define NBLK 1600    // dtw blocks (2 problems each)

__device__ __forceinline__ unsigned ordered_key(float f) {
    unsigned u = __float_as_uint(f);
    return (u & 0x80000000u) ? ~u : (u | 0x80000000u);
}

// ---------------- Kernel 1: per-batch top-50 (exact lax.top_k order) -----
// One 1024-thread block per batch; shfl-based scans (2 block barriers total
// beyond LDS-phase fences). Also resets the dtw election counter.
__global__ __launch_bounds__(1024) void topk_kernel(const float* __restrict__ mask,
                                                    int* __restrict__ topkOut,
                                                    unsigned* __restrict__ counter) {
    __shared__ union {
        unsigned hist[NBIN];                                   // 128 KB
        struct { unsigned ck[CAP]; unsigned ci[CAP]; } c;      // 16 KB
    } U;
    __shared__ unsigned wtot[16], wsuf[16];
    __shared__ unsigned s_bin, ncand;

    const int tid  = threadIdx.x;
    const int w    = tid >> 6;
    const int lane = tid & 63;
    const int b    = blockIdx.x;
    if (b == 0 && tid == 0) *counter = 0;     // reset election counter for dtw
    if (tid == 0) ncand = 0;

    const float4* m4 = (const float4*)(mask + (size_t)b * HW);
    #pragma unroll
    for (int k = 0; k < NBIN / 1024; ++k) U.hist[tid + 1024 * k] = 0;
    __syncthreads();

    for (int c = tid; c < HW / 4; c += 1024) {
        float4 v = m4[c];
        atomicAdd(&U.hist[ordered_key(v.x) >> 17], 1u);
        atomicAdd(&U.hist[ordered_key(v.y) >> 17], 1u);
        atomicAdd(&U.hist[ordered_key(v.z) >> 17], 1u);
        atomicAdd(&U.hist[ordered_key(v.w) >> 17], 1u);
    }
    __syncthreads();

    // per-thread partial over 32 bins (rotated reads -> 2-way conflict = free)
    int base = tid * 32;
    int rot  = tid & 31;
    unsigned p = 0;
    #pragma unroll
    for (int k = 0; k < 32; ++k) p += U.hist[base + ((k + rot) & 31)];

    // wave-level inclusive suffix scan (registers, no barriers)
    unsigned v = p;
    #pragma unroll
    for (int off = 1; off < 64; off <<= 1) {
        unsigned t = __shfl_down(v, off);
        if (lane + off < 64) v += t;
    }
    if (lane == 0) wtot[w] = v;
    __syncthreads();
    if (w == 0 && lane < 16) {
        unsigned x = wtot[lane];
        unsigned y = x;
        #pragma unroll
        for (int off = 1; off < 16; off <<= 1) {
            unsigned t = __shfl_down(y, off);
            if (lane + off < 16) y += t;
        }
        wsuf[lane] = y - x;           // exclusive suffix over higher waves
    }
    __syncthreads();

    {   // find crossing bin: max bin with S(bin) >= PIX
        unsigned Sprev = (v - p) + wsuf[w];     // S(32t+32)
        for (int bsub = 31; bsub >= 0; --bsub) {
            unsigned S = Sprev + U.hist[base + bsub];
            if (S >= PIX && Sprev < PIX) s_bin = (unsigned)(base + bsub);
            Sprev = S;
        }
    }
    __syncthreads();                  // all hist reads done; cand may alias
    unsigned thresh = s_bin << 17;

    for (int c = tid; c < HW / 4; c += 1024) {
        float4 v4 = m4[c];
        float vv[4] = {v4.x, v4.y, v4.z, v4.w};
        #pragma unroll
        for (int e = 0; e < 4; ++e) {
            unsigned key = ordered_key(vv[e]);
            if (key >= thresh) {
                unsigned pos = atomicAdd(&ncand, 1u);
                if (pos < CAP) { U.c.ck[pos] = key; U.c.ci[pos] = (unsigned)(4 * c + e); }
            }
        }
    }
    __syncthreads();

    int nc = (int)min(ncand, (unsigned)CAP);
    for (int c = tid; c < nc; c += 1024) {
        unsigned long long me =
            ((unsigned long long)U.c.ck[c] << 32) | (unsigned long long)(~U.c.ci[c]);
        int rank = 0;
        for (int j = 0; j < nc; ++j) {
            unsigned long long o =
                ((unsigned long long)U.c.ck[j] << 32) | (unsigned long long)(~U.c.ci[j]);
            rank += (o > me);
        }
        if (rank < PIX) topkOut[b * PIX + rank] = (int)U.c.ci[c];
    }
}

// ---------------- Kernel 2: soft-DTW fwd+bwd + fused final reduce --------
// One wave per block, 2 problems per wave (lanes 0-23 / 32-55), register
// wavefront, zero barriers. Last finished block reduces all partials.
__global__ __launch_bounds__(64, 1) void dtw_kernel(
        const float* __restrict__ pred, const float* __restrict__ truth,
        const int* __restrict__ topkIn, float2* __restrict__ parts,
        unsigned* __restrict__ counter, float* __restrict__ out) {
    __shared__ float Rr[64][27];     // stride 27: 26*lane mod 32 -> 2-way, free
    __shared__ float P[64];

    const int lane = threadIdx.x;
    const int half = lane >> 5;
    const int r    = lane & 31;
    const bool rowAct = (r < NN);

    const int np  = 2 * blockIdx.x + half;    // global problem 0..3199
    const int b   = np / PIX;
    const int npb = np - b * PIX;             // within-batch problem 0..49

    float tv = 0.0f, pv = 0.0f;
    if (rowAct) {
        int f  = npb * NN + r;                // within-batch flat (t,p) index
        int t  = f / PIX;
        int pp = f - t * PIX;
        size_t a = (size_t)(b * TT + t) * HW + (size_t)topkIn[b * PIX + pp];
        tv = truth[a];
        pv = pred[a];
    }
    P[lane] = pv;

    // ---- forward: lane r holds row i=r+1; step s computes R[i][s-i] ----
    float Rprev = BIGF, Rprev2 = BIGF;        // R[i][j-1], R[i][j-2]
    #pragma unroll
    for (int s = 2; s <= 2 * NN; ++s) {
        int j = s - 1 - r;
        bool act = rowAct && (j >= 1) && (j <= NN);
        float up   = __shfl_up(Rprev, 1);     // R[i-1][j]
        float diag = __shfl_up(Rprev2, 1);    // R[i-1][j-1]
        int jc = j - 1; jc = jc < 0 ? 0 : (jc > NN - 1 ? NN - 1 : jc);
        float pj = P[(half << 5) + jc];
        if (r == 0) { up = BIGF; diag = (s == 2) ? 0.0f : BIGF; }
        float mn = fminf(diag, fminf(up, Rprev));
        float z = __expf((mn - diag) * INVG) + __expf((mn - up) * INVG)
                + __expf((mn - Rprev) * INVG);
        float d = tv - pj;
        float Rnew = d * d + mn - GAMMA_F * __logf(z);
        if (act) {
            Rr[lane][j - 1] = Rnew;           // stage for backward
            Rprev2 = Rprev;
            Rprev  = Rnew;
        }
    }
    float accS = 0.0f, accT = 0.0f;
    if (r == NN - 1) accS = Rprev;            // R[24][24] (loss_shape)

    // ---- backward: E[i][j] = a*E[i+1][j] + b*E[i][j+1] + c*E[i+1][j+1] --
    float Eprev = 0.0f, Eprev2 = 0.0f;        // own E[i][j+1], E[i][j+2]
    if (r == NN - 1) Eprev = 1.0f;            // E[24][24]=1 (Omega term = 0)
    float tnext = __shfl_down(tv, 1);         // t[i] (row i+1's value)
    #pragma unroll
    for (int s = 2 * NN - 1; s >= 2; --s) {
        int j = s - 1 - r;
        bool act = rowAct && (j >= 1) && (j <= NN);
        float eUp   = __shfl_down(Eprev, 1);  // E[i+1][j]
        float eDiag = __shfl_down(Eprev2, 1); // E[i+1][j+1]
        int jc  = j - 1; jc  = jc  < 0 ? 0 : (jc  > NN - 1 ? NN - 1 : jc);
        int jc2 = j;     jc2 = jc2 < 0 ? 0 : (jc2 > NN - 1 ? NN - 1 : jc2);
        int lup = (r < NN - 1) ? lane + 1 : lane;
        float rij    = Rr[lane][jc];
        float rRight = (j >= NN)                ? -INFINITY : Rr[lane][jc2];
        float rDown  = (r == NN - 1)            ? -INFINITY : Rr[lup][jc];
        float rDiag  = (r == NN - 1 || j >= NN) ? -INFINITY : Rr[lup][jc2];
        float pjm1 = P[(half << 5) + jc];
        float pj   = P[(half << 5) + jc2];
        float da = tnext - pjm1; da *= da;    // D[i+1][j]
        float db = tv - pj;      db *= db;    // D[i][j+1]
        float dc = tnext - pj;   dc *= dc;    // D[i+1][j+1]
        float aw = __expf((rDown  - rij - da) * INVG);
        float bw = __expf((rRight - rij - db) * INVG);
        float cw = __expf((rDiag  - rij - dc) * INVG);
        float Enew = aw * eUp + bw * Eprev + cw * eDiag;
        if (act) {
            float dd = (float)(r + 1 - j);
            accT += Enew * dd * dd;           // E * Omega, own row slice
            Eprev2 = Eprev;
            Eprev  = Enew;
        }
    }

    // ---- wave butterfly (deterministic) + partial store ----
    #pragma unroll
    for (int off = 32; off > 0; off >>= 1) {
        accS += __shfl_xor(accS, off);
        accT += __shfl_xor(accT, off);
    }
    if (lane == 0) parts[blockIdx.x] = make_float2(accS, accT);
    __threadfence();                          // release partials device-wide

    unsigned old = 0;
    if (lane == 0) old = atomicAdd(counter, 1u);
    old = __shfl(old, 0);
    if (old == NBLK - 1) {                    // last block: fixed-order reduce
        __threadfence();                      // acquire all partials
        double S = 0.0, T = 0.0;
        for (int i = lane; i < NBLK; i += 64) {
            float2 v = parts[i];
            S += (double)v.x;
            T += (double)v.y;
        }
        #pragma unroll
        for (int off = 32; off > 0; off >>= 1) {
            S += __shfl_xor(S, off);
            T += __shfl_xor(T, off);
        }
        if (lane == 0) {
            double loss_shape    = S / (double)(BATCH * PIX);
            double loss_temporal = T / ((double)(BATCH * PIX) * (double)(NN * NN));
            out[0] = (float)(0.1 * loss_shape + 0.9 * loss_temporal);
        }
    }
}

extern "C" void kernel_launch(void* const* d_in, const int* in_sizes, int n_in,
                              void* d_out, int out_size, void* d_ws, size_t ws_size,
                              hipStream_t stream) {
    const float* pred  = (const float*)d_in[0];
    const float* truth = (const float*)d_in[1];
    const float* mask  = (const float*)d_in[2];

    float2*   parts   = (float2*)d_ws;                         // 1600*8 = 12.8 KB
    unsigned* counter = (unsigned*)((char*)d_ws + NBLK * sizeof(float2));
    int*      topk    = (int*)((char*)d_ws + NBLK * sizeof(float2) + 256);

    topk_kernel<<<BATCH, 1024, 0, stream>>>(mask, topk, counter);
    dtw_kernel<<<NBLK, 64, 0, stream>>>(pred, truth, topk, parts, counter, (float*)d_out);
}

// Round 6
// 64.030 us; speedup vs baseline: 3.6218x; 1.9610x over previous
//
#include <hip/hip_runtime.h>
#include <math.h>

#define BATCH 64
#define TT 24
#define HW 65536
#define PIX 50
#define NN 24
#define GAMMA_F 0.001f
#define INVG 1000.0f
#define BIGF 100000000.0f
#define NBIN 32768     // bins over ordered-key bits [31:17]
#define PARTS 4        // blocks per batch in local top-k
#define PSIZE (HW / PARTS)   // 16384 elements per part
#define CAPL 512       // candidate cap per part
#define NBLK 1600      // dtw blocks (2 problems each)
#define NCAND (PARTS * PIX)  // 200 candidates per batch

__device__ __forceinline__ unsigned ordered_key(float f) {
    unsigned u = __float_as_uint(f);
    return (u & 0x80000000u) ? ~u : (u | 0x80000000u);
}

// ---------------- Kernel 1: per-quarter exact local top-50 ---------------
// 256 blocks (4 per batch), 16K elements each: radix histogram + exact rank.
// Emits packed (key,~idx) u64 so that larger == better under
// (value desc, index asc) — exact lax.top_k tie semantics.
__global__ __launch_bounds__(1024) void topk_local_kernel(
        const float* __restrict__ mask, unsigned long long* __restrict__ cands) {
    __shared__ union {
        unsigned hist[NBIN];                                   // 128 KB
        struct { unsigned ck[CAPL]; unsigned ci[CAPL]; } c;    // 4 KB
    } U;
    __shared__ unsigned wtot[16], wsuf[16];
    __shared__ unsigned s_bin, ncand;

    const int tid  = threadIdx.x;
    const int w    = tid >> 6;
    const int lane = tid & 63;
    const int b    = blockIdx.x >> 2;
    const int part = blockIdx.x & 3;
    if (tid == 0) ncand = 0;

    const float4* m4 = (const float4*)(mask + (size_t)b * HW + part * PSIZE);
    #pragma unroll
    for (int k = 0; k < NBIN / 1024; ++k) U.hist[tid + 1024 * k] = 0;
    __syncthreads();

    // ---- histogram over this part's 16K elements (4 float4 iters/thread) ----
    for (int c = tid; c < PSIZE / 4; c += 1024) {
        float4 v = m4[c];
        atomicAdd(&U.hist[ordered_key(v.x) >> 17], 1u);
        atomicAdd(&U.hist[ordered_key(v.y) >> 17], 1u);
        atomicAdd(&U.hist[ordered_key(v.z) >> 17], 1u);
        atomicAdd(&U.hist[ordered_key(v.w) >> 17], 1u);
    }
    __syncthreads();

    // ---- per-thread partial over 32 bins (rotated -> 2-way conflict, free) ----
    int base = tid * 32;
    int rot  = tid & 31;
    unsigned p = 0;
    #pragma unroll
    for (int k = 0; k < 32; ++k) p += U.hist[base + ((k + rot) & 31)];

    // wave-level inclusive suffix scan (registers)
    unsigned v = p;
    #pragma unroll
    for (int off = 1; off < 64; off <<= 1) {
        unsigned t = __shfl_down(v, off);
        if (lane + off < 64) v += t;
    }
    if (lane == 0) wtot[w] = v;
    __syncthreads();
    if (w == 0 && lane < 16) {
        unsigned x = wtot[lane];
        unsigned y = x;
        #pragma unroll
        for (int off = 1; off < 16; off <<= 1) {
            unsigned t = __shfl_down(y, off);
            if (lane + off < 16) y += t;
        }
        wsuf[lane] = y - x;           // exclusive suffix over higher waves
    }
    __syncthreads();

    {   // find crossing bin: max bin with S(bin) >= PIX (local k = 50)
        unsigned Sprev = (v - p) + wsuf[w];     // S(32t+32)
        for (int bsub = 31; bsub >= 0; --bsub) {
            unsigned S = Sprev + U.hist[base + bsub];
            if (S >= PIX && Sprev < PIX) s_bin = (unsigned)(base + bsub);
            Sprev = S;
        }
    }
    __syncthreads();                  // all hist reads done; cand may alias
    unsigned thresh = s_bin << 17;

    // ---- collect candidates from own slice (global within-batch index) ----
    for (int c = tid; c < PSIZE / 4; c += 1024) {
        float4 v4 = m4[c];
        float vv[4] = {v4.x, v4.y, v4.z, v4.w};
        #pragma unroll
        for (int e = 0; e < 4; ++e) {
            unsigned key = ordered_key(vv[e]);
            if (key >= thresh) {
                unsigned pos = atomicAdd(&ncand, 1u);
                if (pos < CAPL) {
                    U.c.ck[pos] = key;
                    U.c.ci[pos] = (unsigned)(part * PSIZE + 4 * c + e);
                }
            }
        }
    }
    __syncthreads();

    // ---- exact local ranking; write local top-50 packed ----
    int nc = (int)min(ncand, (unsigned)CAPL);
    for (int c = tid; c < nc; c += 1024) {
        unsigned long long me =
            ((unsigned long long)U.c.ck[c] << 32) | (unsigned long long)(~U.c.ci[c]);
        int rank = 0;
        for (int j = 0; j < nc; ++j) {
            unsigned long long o =
                ((unsigned long long)U.c.ck[j] << 32) | (unsigned long long)(~U.c.ci[j]);
            rank += (o > me);
        }
        if (rank < PIX) cands[(size_t)blockIdx.x * PIX + rank] = me;
    }
}

// ---------------- Kernel 2: merge-200 + soft-DTW fwd+bwd ----------------
// One wave per block, 2 problems (lanes 0-23 / 32-55), register wavefront.
__global__ __launch_bounds__(64, 2) void dtw_kernel(
        const float* __restrict__ pred, const float* __restrict__ truth,
        const unsigned long long* __restrict__ cands, float2* __restrict__ parts) {
    __shared__ unsigned long long cl[NCAND];
    __shared__ int topIdx[PIX];
    __shared__ float Rr[64][27];     // stride 27 floats: odd -> conflict-free
    __shared__ float P[64];

    const int lane = threadIdx.x;
    const int half = lane >> 5;
    const int r    = lane & 31;
    const bool rowAct = (r < NN);

    const int np  = 2 * blockIdx.x + half;    // global problem 0..3199
    const int b   = np / PIX;
    const int npb = np - b * PIX;             // within-batch problem 0..49

    // ---- merge this batch's 4x50 candidates -> exact batch top-50 ----
    for (int i = lane; i < NCAND; i += 64) cl[i] = cands[(size_t)b * NCAND + i];
    __syncthreads();
    for (int i = lane; i < NCAND; i += 64) {
        unsigned long long me = cl[i];
        int rank = 0;
        for (int j = 0; j < NCAND; ++j) rank += (cl[j] > me);
        if (rank < PIX) topIdx[rank] = (int)(~(unsigned)(me & 0xFFFFFFFFull));
    }
    __syncthreads();

    float tv = 0.0f, pv = 0.0f;
    if (rowAct) {
        int f  = npb * NN + r;                // within-batch flat (t,p) index
        int t  = f / PIX;
        int pp = f - t * PIX;
        size_t a = (size_t)(b * TT + t) * HW + (size_t)topIdx[pp];
        tv = truth[a];
        pv = pred[a];
    }
    P[lane] = pv;

    // ---- forward: lane r holds row i=r+1; step s computes R[i][s-i] ----
    float Rprev = BIGF, Rprev2 = BIGF;        // R[i][j-1], R[i][j-2]
    #pragma unroll
    for (int s = 2; s <= 2 * NN; ++s) {
        int j = s - 1 - r;
        bool act = rowAct && (j >= 1) && (j <= NN);
        float up   = __shfl_up(Rprev, 1);     // R[i-1][j]
        float diag = __shfl_up(Rprev2, 1);    // R[i-1][j-1]
        int jc = j - 1; jc = jc < 0 ? 0 : (jc > NN - 1 ? NN - 1 : jc);
        float pj = P[(half << 5) + jc];
        if (r == 0) { up = BIGF; diag = (s == 2) ? 0.0f : BIGF; }
        float mn = fminf(diag, fminf(up, Rprev));
        float z = __expf((mn - diag) * INVG) + __expf((mn - up) * INVG)
                + __expf((mn - Rprev) * INVG);
        float d = tv - pj;
        float Rnew = d * d + mn - GAMMA_F * __logf(z);
        if (act) {
            Rr[lane][j - 1] = Rnew;           // stage for backward
            Rprev2 = Rprev;
            Rprev  = Rnew;
        }
    }
    float accS = 0.0f, accT = 0.0f;
    if (r == NN - 1) accS = Rprev;            // R[24][24] (loss_shape)

    // ---- backward: E[i][j] = a*E[i+1][j] + b*E[i][j+1] + c*E[i+1][j+1] --
    float Eprev = 0.0f, Eprev2 = 0.0f;        // own E[i][j+1], E[i][j+2]
    if (r == NN - 1) Eprev = 1.0f;            // E[24][24]=1 (Omega term = 0)
    float tnext = __shfl_down(tv, 1);         // t[i] (row i+1's value)
    #pragma unroll
    for (int s = 2 * NN - 1; s >= 2; --s) {
        int j = s - 1 - r;
        bool act = rowAct && (j >= 1) && (j <= NN);
        float eUp   = __shfl_down(Eprev, 1);  // E[i+1][j]
        float eDiag = __shfl_down(Eprev2, 1); // E[i+1][j+1]
        int jc  = j - 1; jc  = jc  < 0 ? 0 : (jc  > NN - 1 ? NN - 1 : jc);
        int jc2 = j;     jc2 = jc2 < 0 ? 0 : (jc2 > NN - 1 ? NN - 1 : jc2);
        int lup = (r < NN - 1) ? lane + 1 : lane;
        float rij    = Rr[lane][jc];
        float rRight = (j >= NN)                ? -INFINITY : Rr[lane][jc2];
        float rDown  = (r == NN - 1)            ? -INFINITY : Rr[lup][jc];
        float rDiag  = (r == NN - 1 || j >= NN) ? -INFINITY : Rr[lup][jc2];
        float pjm1 = P[(half << 5) + jc];
        float pj   = P[(half << 5) + jc2];
        float da = tnext - pjm1; da *= da;    // D[i+1][j]
        float db = tv - pj;      db *= db;    // D[i][j+1]
        float dc = tnext - pj;   dc *= dc;    // D[i+1][j+1]
        float aw = __expf((rDown  - rij - da) * INVG);
        float bw = __expf((rRight - rij - db) * INVG);
        float cw = __expf((rDiag  - rij - dc) * INVG);
        float Enew = aw * eUp + bw * Eprev + cw * eDiag;
        if (act) {
            float dd = (float)(r + 1 - j);
            accT += Enew * dd * dd;           // E * Omega, own row slice
            Eprev2 = Eprev;
            Eprev  = Enew;
        }
    }

    // ---- wave butterfly (deterministic) + plain partial store ----
    #pragma unroll
    for (int off = 32; off > 0; off >>= 1) {
        accS += __shfl_xor(accS, off);
        accT += __shfl_xor(accT, off);
    }
    if (lane == 0) parts[blockIdx.x] = make_float2(accS, accT);
}

// ---------------- Kernel 3: deterministic final reduction ----------------
__global__ void finalize_kernel(const float2* __restrict__ parts,
                                float* __restrict__ out) {
    __shared__ double sd[256];
    __shared__ double td[256];
    int tid = threadIdx.x;
    double s = 0.0, t = 0.0;
    for (int i = tid; i < NBLK; i += 256) {
        float2 v = parts[i];
        s += (double)v.x;
        t += (double)v.y;
    }
    sd[tid] = s; td[tid] = t;
    __syncthreads();
    for (int off = 128; off > 0; off >>= 1) {
        if (tid < off) { sd[tid] += sd[tid + off]; td[tid] += td[tid + off]; }
        __syncthreads();
    }
    if (tid == 0) {
        double loss_shape    = sd[0] / (double)(BATCH * PIX);
        double loss_temporal = td[0] / ((double)(BATCH * PIX) * (double)(NN * NN));
        out[0] = (float)(0.1 * loss_shape + 0.9 * loss_temporal);
    }
}

extern "C" void kernel_launch(void* const* d_in, const int* in_sizes, int n_in,
                              void* d_out, int out_size, void* d_ws, size_t ws_size,
                              hipStream_t stream) {
    const float* pred  = (const float*)d_in[0];
    const float* truth = (const float*)d_in[1];
    const float* mask  = (const float*)d_in[2];

    unsigned long long* cands = (unsigned long long*)d_ws;     // 256*50*8 = 100 KB
    float2* parts = (float2*)((char*)d_ws + (size_t)BATCH * PARTS * PIX * 8);  // 12.8 KB

    topk_local_kernel<<<BATCH * PARTS, 1024, 0, stream>>>(mask, cands);
    dtw_kernel<<<NBLK, 64, 0, stream>>>(pred, truth, cands, parts);
    finalize_kernel<<<1, 256, 0, stream>>>(parts, (float*)d_out);
}